// Round 1
// baseline (478.023 us; speedup 1.0000x reference)
//
#include <hip/hip_runtime.h>
#include <math.h>

#define EMB 256
#define DR  128   // resource feature dim
#define DO  192   // operation feature dim
#define DE  64    // edge_attr dim
#define RPB 8     // resources per block in k_h
#define CHUNK 64  // edges staged per iteration in k_out

__device__ __forceinline__ float leaky(float x) { return x >= 0.f ? x : 0.2f * x; }

// dst[j*rows + k] = src[k*cols + j]   (dst is [cols][rows])
__global__ void k_transpose(float* __restrict__ dst, const float* __restrict__ src,
                            int rows, int cols) {
    int i = blockIdx.x * blockDim.x + threadIdx.x;
    if (i < rows * cols) {
        int k = i % rows;
        int j = i / rows;
        dst[i] = src[k * cols + j];
    }
}

// v[j] = sum_k W_op[k*256+j] * a_op[256+k]
__global__ void k_v(float* __restrict__ v, const float* __restrict__ W_op,
                    const float* __restrict__ a_op) {
    int j = threadIdx.x;
    float acc = 0.f;
    for (int k = 0; k < EMB; k++) acc += W_op[k * EMB + j] * a_op[EMB + k];
    v[j] = acc;
}

// h[r][k] = sum_j resources[r][j] * W_selfT[j][k]   (W_selfT is [128][256])
__global__ void k_h(const float* __restrict__ res, const float* __restrict__ wsT,
                    float* __restrict__ h, int R) {
    __shared__ float rrow[RPB][DR];
    int r0 = blockIdx.x * RPB;
    int k = threadIdx.x;
    for (int i = k; i < RPB * DR; i += EMB) {
        int rr = i / DR, j = i % DR;
        rrow[rr][j] = (r0 + rr < R) ? res[(size_t)(r0 + rr) * DR + j] : 0.f;
    }
    __syncthreads();
    float acc[RPB];
#pragma unroll
    for (int rr = 0; rr < RPB; rr++) acc[rr] = 0.f;
    for (int j = 0; j < DR; j++) {
        float w = wsT[j * EMB + k];
#pragma unroll
        for (int rr = 0; rr < RPB; rr++) acc[rr] += rrow[rr][j] * w;
    }
    for (int rr = 0; rr < RPB; rr++)
        if (r0 + rr < R) h[(size_t)(r0 + rr) * EMB + k] = acc[rr];
}

// per-resource: tcross[r] = h[r]·a_op[:256];  p_self[r] = exp(leaky(h[r]·(a_self[:256]+a_self[256:])))
// also atomically accumulates p_self into the global softmax denominator S.
__global__ void k_scores_self(const float* __restrict__ h, const float* __restrict__ a_self,
                              const float* __restrict__ a_op, float* __restrict__ tcross,
                              float* __restrict__ p_self, float* __restrict__ S, int R) {
    int tid = threadIdx.x;
    int lane = tid & 63, wave = tid >> 6;
    int r = blockIdx.x * 4 + wave;
    if (r >= R) return;
    const float* hr = h + (size_t)r * EMB;
    float a1 = 0.f, a2 = 0.f;
#pragma unroll
    for (int q = 0; q < 4; q++) {
        int k = lane + 64 * q;
        float hv = hr[k];
        a1 += hv * (a_self[k] + a_self[EMB + k]);
        a2 += hv * a_op[k];
    }
    for (int m = 1; m < 64; m <<= 1) {
        a1 += __shfl_xor(a1, m, 64);
        a2 += __shfl_xor(a2, m, 64);
    }
    if (lane == 0) {
        float p = expf(leaky(a1));
        p_self[r] = p;
        atomicAdd(S, p);
        tcross[r] = a2;
    }
}

// s_op[o] = operations[o][0:192] · v[0:192]
__global__ void k_sop(const float* __restrict__ ops, const float* __restrict__ v,
                      float* __restrict__ s_op, int O) {
    __shared__ float vv[DO];
    int tid = threadIdx.x;
    if (tid < DO) vv[tid] = v[tid];
    __syncthreads();
    int wave = tid >> 6, lane = tid & 63;
    int o = blockIdx.x * 4 + wave;
    if (o >= O) return;
    const float* row = ops + (size_t)o * DO;
    float acc = row[lane] * vv[lane] + row[lane + 64] * vv[lane + 64] +
                row[lane + 128] * vv[lane + 128];
    for (int m = 1; m < 64; m <<= 1) acc += __shfl_xor(acc, m, 64);
    if (lane == 0) s_op[o] = acc;
}

// per-edge: p_e[e] = exp(leaky(tcross[dst] + s_op[src] + ea[e]·v[192:256])); accumulate sum into S.
__global__ void k_edge_score(const float* __restrict__ ea, const int* __restrict__ esrc,
                             const int* __restrict__ edst, const float* __restrict__ tcross,
                             const float* __restrict__ s_op, const float* __restrict__ v,
                             float* __restrict__ p_e, float* __restrict__ S, int E) {
    __shared__ float v192[DE];
    __shared__ float wsum[4];
    int tid = threadIdx.x;
    if (tid < DE) v192[tid] = v[DO + tid];
    __syncthreads();
    int g = tid >> 4, gl = tid & 15;
    int ngroups = gridDim.x * (blockDim.x >> 4);
    int gid = blockIdx.x * (blockDim.x >> 4) + g;
    float local = 0.f;
    for (int e = gid; e < E; e += ngroups) {
        const float* row = ea + (size_t)e * DE + gl * 4;
        float d = row[0] * v192[gl * 4 + 0] + row[1] * v192[gl * 4 + 1] +
                  row[2] * v192[gl * 4 + 2] + row[3] * v192[gl * 4 + 3];
        d += __shfl_xor(d, 1, 64);
        d += __shfl_xor(d, 2, 64);
        d += __shfl_xor(d, 4, 64);
        d += __shfl_xor(d, 8, 64);
        if (gl == 0) {
            float s = tcross[edst[e]] + s_op[esrc[e]] + d;
            float p = expf(leaky(s));
            p_e[e] = p;
            local += p;
        }
    }
    for (int m = 1; m < 64; m <<= 1) local += __shfl_xor(local, m, 64);
    if ((tid & 63) == 0) wsum[tid >> 6] = local;
    __syncthreads();
    if (tid == 0) atomicAdd(S, wsum[0] + wsum[1] + wsum[2] + wsum[3]);
}

__global__ void k_hist(const int* __restrict__ edst, int* __restrict__ counts, int E) {
    int i = blockIdx.x * blockDim.x + threadIdx.x;
    int n = gridDim.x * blockDim.x;
    for (int e = i; e < E; e += n) atomicAdd(&counts[edst[e]], 1);
}

// exclusive scan of counts[0..R) -> offs[0..R], plus a working copy in cursor.
__global__ void k_scan(const int* __restrict__ counts, int* __restrict__ offs,
                       int* __restrict__ cursor, int R) {
    __shared__ int ps[1024];
    int tid = threadIdx.x;
    int chunk = (R + 1023) >> 10;
    int start = tid * chunk;
    int end = min(start + chunk, R);
    int s = 0;
    for (int i = start; i < end; i++) s += counts[i];
    ps[tid] = s;
    __syncthreads();
    for (int off = 1; off < 1024; off <<= 1) {
        int add = (tid >= off) ? ps[tid - off] : 0;
        __syncthreads();
        ps[tid] += add;
        __syncthreads();
    }
    int run = ps[tid] - s;  // exclusive base for this thread's chunk
    for (int i = start; i < end; i++) {
        offs[i] = run;
        cursor[i] = run;
        run += counts[i];
    }
    if (tid == 0) offs[R] = ps[1023];
}

__global__ void k_scatter(const int* __restrict__ edst, int* __restrict__ cursor,
                          int* __restrict__ perm, int E) {
    int i = blockIdx.x * blockDim.x + threadIdx.x;
    int n = gridDim.x * blockDim.x;
    for (int e = i; e < E; e += n) {
        int pos = atomicAdd(&cursor[edst[e]], 1);
        perm[pos] = e;
    }
}

// one block per resource: x[c] = sum_{e in edges(r)} p_e * (c<192 ? operations[src_e][c] : ea[e][c-192])
// then out[r][k] = elu( (p_self[r]*h[r][k] + sum_j W_opT[j][k]*x[j]) / S )
__global__ void k_out(const float* __restrict__ ops, const float* __restrict__ ea,
                      const int* __restrict__ esrc, const int* __restrict__ perm,
                      const int* __restrict__ offs, const float* __restrict__ p_e,
                      const float* __restrict__ wT, const float* __restrict__ h,
                      const float* __restrict__ p_self, const float* __restrict__ Sp,
                      float* __restrict__ out) {
    int r = blockIdx.x, c = threadIdx.x;
    __shared__ int se[CHUNK];
    __shared__ float sp[CHUNK];
    __shared__ int ss[CHUNK];
    __shared__ float xs[EMB];
    int beg = offs[r], end = offs[r + 1];
    float x = 0.f;
    for (int base = beg; base < end; base += CHUNK) {
        int n = min(CHUNK, end - base);
        if (c < n) {
            int e = perm[base + c];
            se[c] = e;
            sp[c] = p_e[e];
            ss[c] = esrc[e];
        }
        __syncthreads();
        if (c < DO) {
#pragma unroll 4
            for (int i = 0; i < n; i++) x += sp[i] * ops[(size_t)ss[i] * DO + c];
        } else {
            int cc = c - DO;
#pragma unroll 4
            for (int i = 0; i < n; i++) x += sp[i] * ea[(size_t)se[i] * DE + cc];
        }
        __syncthreads();
    }
    xs[c] = x;
    __syncthreads();
    float acc = 0.f;
    for (int j = 0; j < EMB; j++) acc += wT[j * EMB + c] * xs[j];
    float S = *Sp;
    float val = (p_self[r] * h[(size_t)r * EMB + c] + acc) / S;
    out[(size_t)r * EMB + c] = val > 0.f ? val : expm1f(val);
}

extern "C" void kernel_launch(void* const* d_in, const int* in_sizes, int n_in,
                              void* d_out, int out_size, void* d_ws, size_t ws_size,
                              hipStream_t stream) {
    const float* resources = (const float*)d_in[0];
    const float* operations = (const float*)d_in[1];
    const float* edge_attr = (const float*)d_in[2];
    const float* W_self = (const float*)d_in[3];
    const float* W_op = (const float*)d_in[4];
    const float* a_self = (const float*)d_in[5];
    const float* a_op = (const float*)d_in[6];
    const int* edge_src = (const int*)d_in[7];
    const int* edge_dst = (const int*)d_in[8];
    float* out = (float*)d_out;

    const int R = in_sizes[0] / DR;
    const int O = in_sizes[1] / DO;
    const int E = in_sizes[2] / DE;

    // workspace carve
    float* f = (float*)d_ws;
    float* wsT = f;      f += DR * EMB;        // [128][256] transpose of W_self
    float* wT = f;       f += EMB * EMB;       // [256][256] transpose of W_op
    float* v = f;        f += EMB;             // W_op.T @ a_op[256:]
    float* h = f;        f += (size_t)R * EMB;
    float* tcross = f;   f += R;
    float* p_self = f;   f += R;
    float* s_op = f;     f += O;
    float* p_e = f;      f += E;
    float* S = f;        f += 1;
    int* counts = (int*)f;
    int* offs = counts + R;      // R+1
    int* cursor = offs + R + 1;  // R
    int* perm = cursor + R;      // E

    hipMemsetAsync(counts, 0, (size_t)R * sizeof(int), stream);
    hipMemsetAsync(S, 0, sizeof(float), stream);

    k_transpose<<<(DR * EMB + 255) / 256, 256, 0, stream>>>(wsT, W_self, EMB, DR);
    k_transpose<<<(EMB * EMB + 255) / 256, 256, 0, stream>>>(wT, W_op, EMB, EMB);
    k_v<<<1, EMB, 0, stream>>>(v, W_op, a_op);
    k_h<<<(R + RPB - 1) / RPB, EMB, 0, stream>>>(resources, wsT, h, R);
    k_scores_self<<<(R + 3) / 4, 256, 0, stream>>>(h, a_self, a_op, tcross, p_self, S, R);
    k_sop<<<(O + 3) / 4, 256, 0, stream>>>(operations, v, s_op, O);
    k_edge_score<<<2048, 256, 0, stream>>>(edge_attr, edge_src, edge_dst, tcross, s_op, v,
                                           p_e, S, E);
    k_hist<<<1024, 256, 0, stream>>>(edge_dst, counts, E);
    k_scan<<<1, 1024, 0, stream>>>(counts, offs, cursor, R);
    k_scatter<<<1024, 256, 0, stream>>>(edge_dst, cursor, perm, E);
    k_out<<<R, EMB, 0, stream>>>(operations, edge_attr, edge_src, perm, offs, p_e, wT, h,
                                 p_self, S, out);
}

// Round 2
// 465.146 us; speedup vs baseline: 1.0277x; 1.0277x over previous
//
#include <hip/hip_runtime.h>
#include <math.h>

#define EMB 256
#define DR  128   // resource feature dim
#define DO  192   // operation feature dim
#define DE  64    // edge_attr dim
#define RPB 8     // resources per block in k_h
#define CHUNK 64  // edges staged per iteration in k_gather
#define FRPB 8    // resources per block in k_final

__device__ __forceinline__ float leaky(float x) { return x >= 0.f ? x : 0.2f * x; }

// dst[j*rows + k] = src[k*cols + j]   (dst is [cols][rows])
__global__ void k_transpose(float* __restrict__ dst, const float* __restrict__ src,
                            int rows, int cols) {
    int i = blockIdx.x * blockDim.x + threadIdx.x;
    if (i < rows * cols) {
        int k = i % rows;
        int j = i / rows;
        dst[i] = src[k * cols + j];
    }
}

// v[j] += sum_{k in block chunk} W_op[k*256+j] * a_op[256+k]   (v pre-zeroed)
#define KV_CH 8
__global__ void k_v(float* __restrict__ v, const float* __restrict__ W_op,
                    const float* __restrict__ a_op) {
    int j = threadIdx.x;
    int k0 = blockIdx.x * KV_CH;
    float acc = 0.f;
#pragma unroll
    for (int u = 0; u < KV_CH; u++)
        acc += W_op[(size_t)(k0 + u) * EMB + j] * a_op[EMB + k0 + u];
    atomicAdd(&v[j], acc);
}

// h[r][k] = sum_j resources[r][j] * W_selfT[j][k]   (W_selfT is [128][256])
__global__ void k_h(const float* __restrict__ res, const float* __restrict__ wsT,
                    float* __restrict__ h, int R) {
    __shared__ float rrow[RPB][DR];
    int r0 = blockIdx.x * RPB;
    int k = threadIdx.x;
    for (int i = k; i < RPB * DR; i += EMB) {
        int rr = i / DR, j = i % DR;
        rrow[rr][j] = (r0 + rr < R) ? res[(size_t)(r0 + rr) * DR + j] : 0.f;
    }
    __syncthreads();
    float acc[RPB];
#pragma unroll
    for (int rr = 0; rr < RPB; rr++) acc[rr] = 0.f;
    for (int j = 0; j < DR; j++) {
        float w = wsT[j * EMB + k];
#pragma unroll
        for (int rr = 0; rr < RPB; rr++) acc[rr] += rrow[rr][j] * w;
    }
    for (int rr = 0; rr < RPB; rr++)
        if (r0 + rr < R) h[(size_t)(r0 + rr) * EMB + k] = acc[rr];
}

// per-resource: tcross[r] = h[r]·a_op[:256];  p_self[r] = exp(leaky(h[r]·(a_self[:256]+a_self[256:])))
__global__ void k_scores_self(const float* __restrict__ h, const float* __restrict__ a_self,
                              const float* __restrict__ a_op, float* __restrict__ tcross,
                              float* __restrict__ p_self, float* __restrict__ S, int R) {
    int tid = threadIdx.x;
    int lane = tid & 63, wave = tid >> 6;
    int r = blockIdx.x * 4 + wave;
    if (r >= R) return;
    const float* hr = h + (size_t)r * EMB;
    float a1 = 0.f, a2 = 0.f;
#pragma unroll
    for (int q = 0; q < 4; q++) {
        int k = lane + 64 * q;
        float hv = hr[k];
        a1 += hv * (a_self[k] + a_self[EMB + k]);
        a2 += hv * a_op[k];
    }
    for (int m = 1; m < 64; m <<= 1) {
        a1 += __shfl_xor(a1, m, 64);
        a2 += __shfl_xor(a2, m, 64);
    }
    if (lane == 0) {
        float p = expf(leaky(a1));
        p_self[r] = p;
        atomicAdd(S, p);
        tcross[r] = a2;
    }
}

// s_op[o] = operations[o][0:192] · v[0:192]
__global__ void k_sop(const float* __restrict__ ops, const float* __restrict__ v,
                      float* __restrict__ s_op, int O) {
    __shared__ float vv[DO];
    int tid = threadIdx.x;
    if (tid < DO) vv[tid] = v[tid];
    __syncthreads();
    int wave = tid >> 6, lane = tid & 63;
    int o = blockIdx.x * 4 + wave;
    if (o >= O) return;
    const float* row = ops + (size_t)o * DO;
    float acc = row[lane] * vv[lane] + row[lane + 64] * vv[lane + 64] +
                row[lane + 128] * vv[lane + 128];
    for (int m = 1; m < 64; m <<= 1) acc += __shfl_xor(acc, m, 64);
    if (lane == 0) s_op[o] = acc;
}

// per-edge: p_e[e] = exp(leaky(tcross[dst] + s_op[src] + ea[e]·v[192:256])); accumulate sum into S.
__global__ void k_edge_score(const float* __restrict__ ea, const int* __restrict__ esrc,
                             const int* __restrict__ edst, const float* __restrict__ tcross,
                             const float* __restrict__ s_op, const float* __restrict__ v,
                             float* __restrict__ p_e, float* __restrict__ S, int E) {
    __shared__ float wsum[4];
    int tid = threadIdx.x;
    int g = tid >> 4, gl = tid & 15;
    float4 vv = *(const float4*)(v + DO + gl * 4);
    int ngroups = gridDim.x * (blockDim.x >> 4);
    int gid = blockIdx.x * (blockDim.x >> 4) + g;
    float local = 0.f;
    for (int e = gid; e < E; e += ngroups) {
        float4 rv = *(const float4*)(ea + (size_t)e * DE + gl * 4);
        float d = rv.x * vv.x + rv.y * vv.y + rv.z * vv.z + rv.w * vv.w;
        d += __shfl_xor(d, 1, 64);
        d += __shfl_xor(d, 2, 64);
        d += __shfl_xor(d, 4, 64);
        d += __shfl_xor(d, 8, 64);
        if (gl == 0) {
            float s = tcross[edst[e]] + s_op[esrc[e]] + d;
            float p = expf(leaky(s));
            p_e[e] = p;
            local += p;
        }
    }
    for (int m = 1; m < 64; m <<= 1) local += __shfl_xor(local, m, 64);
    if ((tid & 63) == 0) wsum[tid >> 6] = local;
    __syncthreads();
    if (tid == 0) atomicAdd(S, wsum[0] + wsum[1] + wsum[2] + wsum[3]);
}

__global__ void k_hist(const int* __restrict__ edst, int* __restrict__ counts, int E) {
    int i = blockIdx.x * blockDim.x + threadIdx.x;
    int n = gridDim.x * blockDim.x;
    for (int e = i; e < E; e += n) atomicAdd(&counts[edst[e]], 1);
}

// exclusive scan of counts[0..R) -> offs[0..R], plus a working copy in cursor.
__global__ void k_scan(const int* __restrict__ counts, int* __restrict__ offs,
                       int* __restrict__ cursor, int R) {
    __shared__ int ps[1024];
    int tid = threadIdx.x;
    int chunk = (R + 1023) >> 10;
    int start = tid * chunk;
    int end = min(start + chunk, R);
    int s = 0;
    for (int i = start; i < end; i++) s += counts[i];
    ps[tid] = s;
    __syncthreads();
    for (int off = 1; off < 1024; off <<= 1) {
        int add = (tid >= off) ? ps[tid - off] : 0;
        __syncthreads();
        ps[tid] += add;
        __syncthreads();
    }
    int run = ps[tid] - s;  // exclusive base for this thread's chunk
    for (int i = start; i < end; i++) {
        offs[i] = run;
        cursor[i] = run;
        run += counts[i];
    }
    if (tid == 0) offs[R] = ps[1023];
}

// scatter edges into CSR order; also emit p and src in perm order (coalesced reads here,
// so k_gather never has to gather metadata).
__global__ void k_scatter(const int* __restrict__ edst, const int* __restrict__ esrc,
                          const float* __restrict__ p_e, int* __restrict__ cursor,
                          int* __restrict__ perm, int* __restrict__ sperm,
                          float* __restrict__ pperm, int E) {
    int i = blockIdx.x * blockDim.x + threadIdx.x;
    int n = gridDim.x * blockDim.x;
    for (int e = i; e < E; e += n) {
        int pos = atomicAdd(&cursor[edst[e]], 1);
        perm[pos] = e;
        sperm[pos] = esrc[e];
        pperm[pos] = p_e[e];
    }
}

// one block per resource: X[r][c] = sum_{e in edges(r)} p_e * (c<192 ? ops[src_e][c] : ea[e][c-192])
__global__ void k_gather(const float* __restrict__ ops, const float* __restrict__ ea,
                         const int* __restrict__ sperm, const float* __restrict__ pperm,
                         const int* __restrict__ eperm, const int* __restrict__ offs,
                         float* __restrict__ X) {
    int r = blockIdx.x, c = threadIdx.x;
    __shared__ float sp[CHUNK];
    __shared__ int ss[CHUNK];
    __shared__ int se[CHUNK];
    int beg = offs[r], end = offs[r + 1];
    float x = 0.f;
    for (int base = beg; base < end; base += CHUNK) {
        int n = min(CHUNK, end - base);
        if (c < n) {
            sp[c] = pperm[base + c];
            ss[c] = sperm[base + c];
            se[c] = eperm[base + c];
        }
        __syncthreads();
        if (c < DO) {
#pragma unroll 8
            for (int i = 0; i < n; i++) x += sp[i] * ops[(size_t)ss[i] * DO + c];
        } else {
            int cc = c - DO;
#pragma unroll 8
            for (int i = 0; i < n; i++) x += sp[i] * ea[(size_t)se[i] * DE + cc];
        }
        __syncthreads();
    }
    X[(size_t)r * EMB + c] = x;
}

// out[r][c] = elu( (p_self[r]*h[r][c] + sum_j wT[j][c]*X[r][j]) / S )
__global__ void k_final(const float* __restrict__ X, const float* __restrict__ wT,
                        const float* __restrict__ h, const float* __restrict__ p_self,
                        const float* __restrict__ Sp, float* __restrict__ out, int R) {
    __shared__ float xl[FRPB][EMB];
    __shared__ float ps[FRPB];
    int r0 = blockIdx.x * FRPB;
    int t = threadIdx.x;
    for (int i = t; i < FRPB * EMB; i += 256) {
        int rr = i >> 8, j = i & 255;
        xl[rr][j] = (r0 + rr < R) ? X[(size_t)(r0 + rr) * EMB + j] : 0.f;
    }
    if (t < FRPB) ps[t] = (r0 + t < R) ? p_self[r0 + t] : 0.f;
    __syncthreads();
    float acc[FRPB];
#pragma unroll
    for (int rr = 0; rr < FRPB; rr++) acc[rr] = 0.f;
    int c = t;
    for (int j = 0; j < EMB; j += 4) {
        float w0 = wT[(j + 0) * EMB + c];
        float w1 = wT[(j + 1) * EMB + c];
        float w2 = wT[(j + 2) * EMB + c];
        float w3 = wT[(j + 3) * EMB + c];
#pragma unroll
        for (int rr = 0; rr < FRPB; rr++) {
            float4 xv = *(const float4*)&xl[rr][j];
            acc[rr] += xv.x * w0 + xv.y * w1 + xv.z * w2 + xv.w * w3;
        }
    }
    float inv = 1.f / (*Sp);
#pragma unroll
    for (int rr = 0; rr < FRPB; rr++) {
        int r = r0 + rr;
        if (r < R) {
            float val = (ps[rr] * h[(size_t)r * EMB + c] + acc[rr]) * inv;
            out[(size_t)r * EMB + c] = val > 0.f ? val : expm1f(val);
        }
    }
}

extern "C" void kernel_launch(void* const* d_in, const int* in_sizes, int n_in,
                              void* d_out, int out_size, void* d_ws, size_t ws_size,
                              hipStream_t stream) {
    const float* resources = (const float*)d_in[0];
    const float* operations = (const float*)d_in[1];
    const float* edge_attr = (const float*)d_in[2];
    const float* W_self = (const float*)d_in[3];
    const float* W_op = (const float*)d_in[4];
    const float* a_self = (const float*)d_in[5];
    const float* a_op = (const float*)d_in[6];
    const int* edge_src = (const int*)d_in[7];
    const int* edge_dst = (const int*)d_in[8];
    float* out = (float*)d_out;

    const int R = in_sizes[0] / DR;
    const int O = in_sizes[1] / DO;
    const int E = in_sizes[2] / DE;

    // workspace carve
    float* f = (float*)d_ws;
    float* wsT = f;      f += DR * EMB;        // [128][256] transpose of W_self
    float* wT = f;       f += EMB * EMB;       // [256][256] transpose of W_op
    float* v = f;        f += EMB;             // W_op.T @ a_op[256:]
    float* h = f;        f += (size_t)R * EMB;
    float* X = f;        f += (size_t)R * EMB;
    float* tcross = f;   f += R;
    float* p_self = f;   f += R;
    float* s_op = f;     f += O;
    float* p_e = f;      f += E;
    float* pperm = f;    f += E;
    float* S = f;        f += 1;
    int* counts = (int*)f;
    int* offs = counts + R;      // R+1
    int* cursor = offs + R + 1;  // R
    int* perm = cursor + R;      // E
    int* sperm = perm + E;       // E

    hipMemsetAsync(counts, 0, (size_t)R * sizeof(int), stream);
    hipMemsetAsync(S, 0, sizeof(float), stream);
    hipMemsetAsync(v, 0, EMB * sizeof(float), stream);

    k_transpose<<<(DR * EMB + 255) / 256, 256, 0, stream>>>(wsT, W_self, EMB, DR);
    k_transpose<<<(EMB * EMB + 255) / 256, 256, 0, stream>>>(wT, W_op, EMB, EMB);
    k_v<<<EMB / KV_CH, EMB, 0, stream>>>(v, W_op, a_op);
    k_h<<<(R + RPB - 1) / RPB, EMB, 0, stream>>>(resources, wsT, h, R);
    k_scores_self<<<(R + 3) / 4, 256, 0, stream>>>(h, a_self, a_op, tcross, p_self, S, R);
    k_sop<<<(O + 3) / 4, 256, 0, stream>>>(operations, v, s_op, O);
    k_edge_score<<<2048, 256, 0, stream>>>(edge_attr, edge_src, edge_dst, tcross, s_op, v,
                                           p_e, S, E);
    k_hist<<<1024, 256, 0, stream>>>(edge_dst, counts, E);
    k_scan<<<1, 1024, 0, stream>>>(counts, offs, cursor, R);
    k_scatter<<<1024, 256, 0, stream>>>(edge_dst, edge_src, p_e, cursor, perm, sperm,
                                        pperm, E);
    k_gather<<<R, EMB, 0, stream>>>(operations, edge_attr, sperm, pperm, perm, offs, X);
    k_final<<<(R + FRPB - 1) / FRPB, 256, 0, stream>>>(X, wT, h, p_self, S, out, R);
}

// Round 3
// 293.805 us; speedup vs baseline: 1.6270x; 1.5832x over previous
//
#include <hip/hip_runtime.h>
#include <math.h>

#define EMB 256
#define DR  128   // resource feature dim
#define DO  192   // operation feature dim
#define DE  64    // edge_attr dim
#define RPB 8     // resources per block in k_h
#define CHUNK 64  // edges staged per iteration in k_gather
#define FRPB 8    // resources per block in k_final
#define NB_ES 2048  // k_edge_score grid (per-block partial sums)
#define KV_CH 8   // k-rows per block in the v part of k_prep

__device__ __forceinline__ float leaky(float x) { return x >= 0.f ? x : 0.2f * x; }

// Fused prep: blocks [0,128) transpose W_self -> wsT [128][256];
// blocks [128,384) transpose W_op -> wT [256][256];
// blocks [384,416) accumulate v[j] = sum_k W_op[k][j]*a_op[256+k] (v pre-zeroed).
__global__ void k_prep(float* __restrict__ wsT, float* __restrict__ wT,
                       float* __restrict__ v, const float* __restrict__ W_self,
                       const float* __restrict__ W_op, const float* __restrict__ a_op) {
    int b = blockIdx.x, t = threadIdx.x;
    if (b < 128) {
        int i = b * 256 + t;            // wsT flat index
        int k = i & 255, j = i >> 8;    // wsT[j*256+k] = W_self[k*128+j]
        wsT[i] = W_self[k * DR + j];
    } else if (b < 384) {
        int i = (b - 128) * 256 + t;
        int k = i & 255, j = i >> 8;    // wT[j*256+k] = W_op[k*256+j]
        wT[i] = W_op[(size_t)k * EMB + j];
    } else {
        int k0 = (b - 384) * KV_CH;
        float acc = 0.f;
#pragma unroll
        for (int u = 0; u < KV_CH; u++)
            acc += W_op[(size_t)(k0 + u) * EMB + t] * a_op[EMB + k0 + u];
        atomicAdd(&v[t], acc);
    }
}

// h[r][k] = sum_j resources[r][j] * W_selfT[j][k]
__global__ void k_h(const float* __restrict__ res, const float* __restrict__ wsT,
                    float* __restrict__ h, int R) {
    __shared__ float rrow[RPB][DR];
    int r0 = blockIdx.x * RPB;
    int k = threadIdx.x;
    for (int i = k; i < RPB * DR; i += EMB) {
        int rr = i / DR, j = i % DR;
        rrow[rr][j] = (r0 + rr < R) ? res[(size_t)(r0 + rr) * DR + j] : 0.f;
    }
    __syncthreads();
    float acc[RPB];
#pragma unroll
    for (int rr = 0; rr < RPB; rr++) acc[rr] = 0.f;
    for (int j = 0; j < DR; j++) {
        float w = wsT[j * EMB + k];
#pragma unroll
        for (int rr = 0; rr < RPB; rr++) acc[rr] += rrow[rr][j] * w;
    }
    for (int rr = 0; rr < RPB; rr++)
        if (r0 + rr < R) h[(size_t)(r0 + rr) * EMB + k] = acc[rr];
}

// per-resource: tcross[r] = h[r]·a_op[:256];  p_self[r] = exp(leaky(h[r]·(a_self[:256]+a_self[256:])))
// NO atomics — S is reduced later in k_scan.
__global__ void k_scores_self(const float* __restrict__ h, const float* __restrict__ a_self,
                              const float* __restrict__ a_op, float* __restrict__ tcross,
                              float* __restrict__ p_self, int R) {
    int tid = threadIdx.x;
    int lane = tid & 63, wave = tid >> 6;
    int r = blockIdx.x * 4 + wave;
    if (r >= R) return;
    const float* hr = h + (size_t)r * EMB;
    float a1 = 0.f, a2 = 0.f;
#pragma unroll
    for (int q = 0; q < 4; q++) {
        int k = lane + 64 * q;
        float hv = hr[k];
        a1 += hv * (a_self[k] + a_self[EMB + k]);
        a2 += hv * a_op[k];
    }
    for (int m = 1; m < 64; m <<= 1) {
        a1 += __shfl_xor(a1, m, 64);
        a2 += __shfl_xor(a2, m, 64);
    }
    if (lane == 0) {
        p_self[r] = expf(leaky(a1));
        tcross[r] = a2;
    }
}

// s_op[o] = operations[o][0:192] · v[0:192]
__global__ void k_sop(const float* __restrict__ ops, const float* __restrict__ v,
                      float* __restrict__ s_op, int O) {
    __shared__ float vv[DO];
    int tid = threadIdx.x;
    if (tid < DO) vv[tid] = v[tid];
    __syncthreads();
    int wave = tid >> 6, lane = tid & 63;
    int o = blockIdx.x * 4 + wave;
    if (o >= O) return;
    const float* row = ops + (size_t)o * DO;
    float acc = row[lane] * vv[lane] + row[lane + 64] * vv[lane + 64] +
                row[lane + 128] * vv[lane + 128];
    for (int m = 1; m < 64; m <<= 1) acc += __shfl_xor(acc, m, 64);
    if (lane == 0) s_op[o] = acc;
}

// per-edge: p_e[e] = exp(leaky(tcross[dst] + s_op[src] + ea[e]·v[192:256]))
// fused: histogram of edge_dst into counts; per-block partial sum -> esum[blockIdx].
__global__ void k_edge_score(const float* __restrict__ ea, const int* __restrict__ esrc,
                             const int* __restrict__ edst, const float* __restrict__ tcross,
                             const float* __restrict__ s_op, const float* __restrict__ v,
                             float* __restrict__ p_e, float* __restrict__ esum,
                             int* __restrict__ counts, int E) {
    __shared__ float wsum[4];
    int tid = threadIdx.x;
    int g = tid >> 4, gl = tid & 15;
    float4 vv = *(const float4*)(v + DO + gl * 4);
    int ngroups = gridDim.x * (blockDim.x >> 4);
    int gid = blockIdx.x * (blockDim.x >> 4) + g;
    float local = 0.f;
    for (int e = gid; e < E; e += ngroups) {
        float4 rv = *(const float4*)(ea + (size_t)e * DE + gl * 4);
        float d = rv.x * vv.x + rv.y * vv.y + rv.z * vv.z + rv.w * vv.w;
        d += __shfl_xor(d, 1, 64);
        d += __shfl_xor(d, 2, 64);
        d += __shfl_xor(d, 4, 64);
        d += __shfl_xor(d, 8, 64);
        if (gl == 0) {
            int dst = edst[e];
            float s = tcross[dst] + s_op[esrc[e]] + d;
            float p = expf(leaky(s));
            p_e[e] = p;
            local += p;
            atomicAdd(&counts[dst], 1);
        }
    }
    for (int m = 1; m < 64; m <<= 1) local += __shfl_xor(local, m, 64);
    if ((tid & 63) == 0) wsum[tid >> 6] = local;
    __syncthreads();
    if (tid == 0) esum[blockIdx.x] = wsum[0] + wsum[1] + wsum[2] + wsum[3];
}

// single block: exclusive scan of counts -> offs/cursor, and deterministic
// reduction S = sum(p_self) + sum(esum).
__global__ void k_scan(const int* __restrict__ counts, int* __restrict__ offs,
                       int* __restrict__ cursor, int R, const float* __restrict__ p_self,
                       const float* __restrict__ esum, int nesum, float* __restrict__ S) {
    __shared__ int ps[1024];
    __shared__ float fs[1024];
    int tid = threadIdx.x;
    int chunk = (R + 1023) >> 10;
    int start = tid * chunk;
    int end = min(start + chunk, R);
    int s = 0;
    for (int i = start; i < end; i++) s += counts[i];
    ps[tid] = s;
    float fv = 0.f;
    for (int i = tid; i < R; i += 1024) fv += p_self[i];
    for (int i = tid; i < nesum; i += 1024) fv += esum[i];
    fs[tid] = fv;
    __syncthreads();
    for (int off = 1; off < 1024; off <<= 1) {
        int add = (tid >= off) ? ps[tid - off] : 0;
        __syncthreads();
        ps[tid] += add;
        __syncthreads();
    }
    int run = ps[tid] - s;  // exclusive base for this thread's chunk
    for (int i = start; i < end; i++) {
        offs[i] = run;
        cursor[i] = run;
        run += counts[i];
    }
    if (tid == 0) offs[R] = ps[1023];
    for (int off = 512; off > 0; off >>= 1) {
        __syncthreads();
        if (tid < off) fs[tid] += fs[tid + off];
    }
    if (tid == 0) *S = fs[0];
}

// scatter edges into CSR order; emit p and src in perm order too.
__global__ void k_scatter(const int* __restrict__ edst, const int* __restrict__ esrc,
                          const float* __restrict__ p_e, int* __restrict__ cursor,
                          int* __restrict__ perm, int* __restrict__ sperm,
                          float* __restrict__ pperm, int E) {
    int i = blockIdx.x * blockDim.x + threadIdx.x;
    int n = gridDim.x * blockDim.x;
    for (int e = i; e < E; e += n) {
        int pos = atomicAdd(&cursor[edst[e]], 1);
        perm[pos] = e;
        sperm[pos] = esrc[e];
        pperm[pos] = p_e[e];
    }
}

// one block per resource. 4 waves: waves 0-2 own ops col-groups, wave 3 owns ea cols.
// Within a wave: lane l -> edge-slot eidx=l>>4, float4 col-group g = w*16 + (l&15).
// X[r][4g..4g+3] = sum_e p_e * (g<48 ? ops[src][4g..] : ea[e][4(g-48)..])
__global__ void k_gather(const float* __restrict__ ops, const float* __restrict__ ea,
                         const int* __restrict__ sperm, const float* __restrict__ pperm,
                         const int* __restrict__ eperm, const int* __restrict__ offs,
                         float* __restrict__ X) {
    int r = blockIdx.x;
    int t = threadIdx.x;
    int w = t >> 6, l = t & 63;
    int eidx = l >> 4, sub = l & 15;
    int beg = offs[r], end = offs[r + 1];
    int cnt = end - beg;
    __shared__ float sp[CHUNK];
    __shared__ int ss[CHUNK];
    __shared__ int se[CHUNK];
    float4 acc = {0.f, 0.f, 0.f, 0.f};
    const bool isea = (w == 3);
    const int coff = isea ? sub * 4 : (w * 16 + sub) * 4;  // within-row float offset
    for (int base = 0; base < cnt; base += CHUNK) {
        if (t < CHUNK) {
            int idx = beg + base + t;
            bool valid = idx < end;
            sp[t] = valid ? pperm[idx] : 0.f;
            ss[t] = valid ? sperm[idx] : 0;
            se[t] = valid ? eperm[idx] : 0;
        }
        __syncthreads();
        int n = min(CHUNK, cnt - base);
        int nit = (n + 3) >> 2;
        if (isea) {
#pragma unroll 4
            for (int it = 0; it < nit; it++) {
                int i = it * 4 + eidx;
                float4 rv = *(const float4*)(ea + (size_t)se[i] * DE + coff);
                float p = sp[i];
                acc.x += p * rv.x; acc.y += p * rv.y;
                acc.z += p * rv.z; acc.w += p * rv.w;
            }
        } else {
#pragma unroll 4
            for (int it = 0; it < nit; it++) {
                int i = it * 4 + eidx;
                float4 rv = *(const float4*)(ops + (size_t)ss[i] * DO + coff);
                float p = sp[i];
                acc.x += p * rv.x; acc.y += p * rv.y;
                acc.z += p * rv.z; acc.w += p * rv.w;
            }
        }
        __syncthreads();
    }
    // reduce over the 4 edge-slots (lanes l, l^16, l^32 pattern covers {sub, sub+16, sub+32, sub+48})
    acc.x += __shfl_xor(acc.x, 16, 64); acc.y += __shfl_xor(acc.y, 16, 64);
    acc.z += __shfl_xor(acc.z, 16, 64); acc.w += __shfl_xor(acc.w, 16, 64);
    acc.x += __shfl_xor(acc.x, 32, 64); acc.y += __shfl_xor(acc.y, 32, 64);
    acc.z += __shfl_xor(acc.z, 32, 64); acc.w += __shfl_xor(acc.w, 32, 64);
    if (l < 16) {
        int g = w * 16 + l;  // float4 group in X row (0..63)
        *(float4*)(X + (size_t)r * EMB + g * 4) = acc;
    }
}

// out[r][c] = elu( (p_self[r]*h[r][c] + sum_j wT[j][c]*X[r][j]) / S )
__global__ void k_final(const float* __restrict__ X, const float* __restrict__ wT,
                        const float* __restrict__ h, const float* __restrict__ p_self,
                        const float* __restrict__ Sp, float* __restrict__ out, int R) {
    __shared__ float xl[FRPB][EMB];
    __shared__ float ps[FRPB];
    int r0 = blockIdx.x * FRPB;
    int t = threadIdx.x;
    for (int i = t; i < FRPB * EMB; i += 256) {
        int rr = i >> 8, j = i & 255;
        xl[rr][j] = (r0 + rr < R) ? X[(size_t)(r0 + rr) * EMB + j] : 0.f;
    }
    if (t < FRPB) ps[t] = (r0 + t < R) ? p_self[r0 + t] : 0.f;
    __syncthreads();
    float acc[FRPB];
#pragma unroll
    for (int rr = 0; rr < FRPB; rr++) acc[rr] = 0.f;
    int c = t;
    for (int j = 0; j < EMB; j += 4) {
        float w0 = wT[(j + 0) * EMB + c];
        float w1 = wT[(j + 1) * EMB + c];
        float w2 = wT[(j + 2) * EMB + c];
        float w3 = wT[(j + 3) * EMB + c];
#pragma unroll
        for (int rr = 0; rr < FRPB; rr++) {
            float4 xv = *(const float4*)&xl[rr][j];
            acc[rr] += xv.x * w0 + xv.y * w1 + xv.z * w2 + xv.w * w3;
        }
    }
    float inv = 1.f / (*Sp);
#pragma unroll
    for (int rr = 0; rr < FRPB; rr++) {
        int r = r0 + rr;
        if (r < R) {
            float val = (ps[rr] * h[(size_t)r * EMB + c] + acc[rr]) * inv;
            out[(size_t)r * EMB + c] = val > 0.f ? val : expm1f(val);
        }
    }
}

extern "C" void kernel_launch(void* const* d_in, const int* in_sizes, int n_in,
                              void* d_out, int out_size, void* d_ws, size_t ws_size,
                              hipStream_t stream) {
    const float* resources = (const float*)d_in[0];
    const float* operations = (const float*)d_in[1];
    const float* edge_attr = (const float*)d_in[2];
    const float* W_self = (const float*)d_in[3];
    const float* W_op = (const float*)d_in[4];
    const float* a_self = (const float*)d_in[5];
    const float* a_op = (const float*)d_in[6];
    const int* edge_src = (const int*)d_in[7];
    const int* edge_dst = (const int*)d_in[8];
    float* out = (float*)d_out;

    const int R = in_sizes[0] / DR;
    const int O = in_sizes[1] / DO;
    const int E = in_sizes[2] / DE;

    // workspace carve — counts and v first so one memset zeroes both
    int* counts = (int*)d_ws;                 // R
    float* v = (float*)(counts + R);          // 256
    float* wsT = v + EMB;                     // 128*256
    float* wT = wsT + DR * EMB;               // 256*256
    float* h = wT + EMB * EMB;                // R*256
    float* X = h + (size_t)R * EMB;           // R*256
    float* tcross = X + (size_t)R * EMB;      // R
    float* p_self = tcross + R;               // R
    float* s_op = p_self + R;                 // O
    float* p_e = s_op + O;                    // E
    float* pperm = p_e + E;                   // E
    float* esum = pperm + E;                  // NB_ES
    float* S = esum + NB_ES;                  // 1
    int* offs = (int*)(S + 1);                // R+1
    int* cursor = offs + R + 1;               // R
    int* perm = cursor + R;                   // E
    int* sperm = perm + E;                    // E

    hipMemsetAsync(d_ws, 0, (size_t)(R + EMB) * sizeof(float), stream);

    k_prep<<<416, 256, 0, stream>>>(wsT, wT, v, W_self, W_op, a_op);
    k_h<<<(R + RPB - 1) / RPB, EMB, 0, stream>>>(resources, wsT, h, R);
    k_scores_self<<<(R + 3) / 4, 256, 0, stream>>>(h, a_self, a_op, tcross, p_self, R);
    k_sop<<<(O + 3) / 4, 256, 0, stream>>>(operations, v, s_op, O);
    k_edge_score<<<NB_ES, 256, 0, stream>>>(edge_attr, edge_src, edge_dst, tcross, s_op, v,
                                            p_e, esum, counts, E);
    k_scan<<<1, 1024, 0, stream>>>(counts, offs, cursor, R, p_self, esum, NB_ES, S);
    k_scatter<<<1024, 256, 0, stream>>>(edge_dst, edge_src, p_e, cursor, perm, sperm,
                                        pperm, E);
    k_gather<<<R, 256, 0, stream>>>(operations, edge_attr, sperm, pperm, perm, offs, X);
    k_final<<<(R + FRPB - 1) / FRPB, 256, 0, stream>>>(X, wT, h, p_self, S, out, R);
}

// Round 4
// 273.631 us; speedup vs baseline: 1.7470x; 1.0737x over previous
//
#include <hip/hip_runtime.h>
#include <math.h>

#define EMB 256
#define DR  128   // resource feature dim
#define DO  192   // operation feature dim
#define DE  64    // edge_attr dim
#define RPB 8     // resources per block in k_h
#define FRPB 16   // resources per block in k_final
#define KV_CH 8   // k-rows per block in the v part of k_prep
#define HB 256    // histogram blocks in k_prep

__device__ __forceinline__ float leaky(float x) { return x >= 0.f ? x : 0.2f * x; }

// Fused prep: blocks [0,128) transpose W_self -> wsT [128][256];
// blocks [128,384) transpose W_op -> wT [256][256];
// blocks [384,416) accumulate v[j] = sum_k W_op[k][j]*a_op[256+k] (v pre-zeroed);
// blocks [416,416+HB) histogram edge_dst into counts (pre-zeroed).
__global__ void k_prep(float* __restrict__ wsT, float* __restrict__ wT,
                       float* __restrict__ v, const float* __restrict__ W_self,
                       const float* __restrict__ W_op, const float* __restrict__ a_op,
                       const int* __restrict__ edst, int* __restrict__ counts, int E) {
    int b = blockIdx.x, t = threadIdx.x;
    if (b < 128) {
        int i = b * 256 + t;            // wsT flat index
        int k = i & 255, j = i >> 8;    // wsT[j*256+k] = W_self[k*128+j]
        wsT[i] = W_self[k * DR + j];
    } else if (b < 384) {
        int i = (b - 128) * 256 + t;
        int k = i & 255, j = i >> 8;    // wT[j*256+k] = W_op[k*256+j]
        wT[i] = W_op[(size_t)k * EMB + j];
    } else if (b < 416) {
        int k0 = (b - 384) * KV_CH;
        float acc = 0.f;
#pragma unroll
        for (int u = 0; u < KV_CH; u++)
            acc += W_op[(size_t)(k0 + u) * EMB + t] * a_op[EMB + k0 + u];
        atomicAdd(&v[t], acc);
    } else {
        int i = (b - 416) * 256 + t;
        int n = HB * 256;
        for (int e = i; e < E; e += n) atomicAdd(&counts[edst[e]], 1);
    }
}

// h[r][k] = sum_j resources[r][j] * wsT[j][k]; fused per-resource scores:
// tcross[r] = h[r]·a_op[:256];  p_self[r] = exp(leaky(h[r]·(a_self[:256]+a_self[256:])))
__global__ void k_h(const float* __restrict__ res, const float* __restrict__ wsT,
                    const float* __restrict__ a_self, const float* __restrict__ a_op,
                    float* __restrict__ h, float* __restrict__ tcross,
                    float* __restrict__ p_self, int R) {
    __shared__ float rrow[RPB][DR];
    __shared__ float red[RPB][4][2];
    int r0 = blockIdx.x * RPB;
    int k = threadIdx.x;
    int w = k >> 6, l = k & 63;
    for (int i = k; i < RPB * DR; i += EMB) {
        int rr = i / DR, j = i % DR;
        rrow[rr][j] = (r0 + rr < R) ? res[(size_t)(r0 + rr) * DR + j] : 0.f;
    }
    __syncthreads();
    float acc[RPB];
#pragma unroll
    for (int rr = 0; rr < RPB; rr++) acc[rr] = 0.f;
    for (int j = 0; j < DR; j++) {
        float wv = wsT[j * EMB + k];
#pragma unroll
        for (int rr = 0; rr < RPB; rr++) acc[rr] += rrow[rr][j] * wv;
    }
    float as_ = a_self[k] + a_self[EMB + k];
    float ao_ = a_op[k];
#pragma unroll
    for (int rr = 0; rr < RPB; rr++) {
        if (r0 + rr < R) h[(size_t)(r0 + rr) * EMB + k] = acc[rr];
        float s1 = acc[rr] * as_;
        float s2 = acc[rr] * ao_;
        for (int m = 1; m < 64; m <<= 1) {
            s1 += __shfl_xor(s1, m, 64);
            s2 += __shfl_xor(s2, m, 64);
        }
        if (l == 0) { red[rr][w][0] = s1; red[rr][w][1] = s2; }
    }
    __syncthreads();
    if (k < RPB) {
        int r = r0 + k;
        if (r < R) {
            float a1 = red[k][0][0] + red[k][1][0] + red[k][2][0] + red[k][3][0];
            float a2 = red[k][0][1] + red[k][1][1] + red[k][2][1] + red[k][3][1];
            p_self[r] = expf(leaky(a1));
            tcross[r] = a2;
        }
    }
}

// single block: exclusive scan of counts -> offs (R+1) and cursor copy.
__global__ void k_scan(const int* __restrict__ counts, int* __restrict__ offs,
                       int* __restrict__ cursor, int R) {
    __shared__ int ps[1024];
    int tid = threadIdx.x;
    int chunk = (R + 1023) >> 10;
    int start = tid * chunk;
    int end = min(start + chunk, R);
    int s = 0;
    for (int i = start; i < end; i++) s += counts[i];
    ps[tid] = s;
    __syncthreads();
    for (int off = 1; off < 1024; off <<= 1) {
        int add = (tid >= off) ? ps[tid - off] : 0;
        __syncthreads();
        ps[tid] += add;
        __syncthreads();
    }
    int run = ps[tid] - s;  // exclusive base for this thread's chunk
    for (int i = start; i < end; i++) {
        offs[i] = run;
        cursor[i] = run;
        run += counts[i];
    }
    if (tid == 0) offs[R] = ps[1023];
}

// scatter edges into CSR order; one 8B struct {src, e} per edge.
__global__ void k_scatter(const int* __restrict__ edst, const int* __restrict__ esrc,
                          int* __restrict__ cursor, int2* __restrict__ meta, int E) {
    int i = blockIdx.x * blockDim.x + threadIdx.x;
    int n = gridDim.x * blockDim.x;
    for (int e = i; e < E; e += n) {
        int pos = atomicAdd(&cursor[edst[e]], 1);
        meta[pos] = make_int2(esrc[e], e);
    }
}

// one block per resource; lane l owns column-group l*4..l*4+3 of the concat row
// (l<48 -> ops cols, l>=48 -> ea cols; X col = l*4 in both cases).
// Per edge (one wave each, j = w + 4*i):
//   t = sum_l dot(rv_l, v[l*4..]) = ops[src]·v[:192] + ea[e]·v[192:]
//   p = exp(leaky(tcross[r] + t));  acc_l += p * rv_l;  psum += p
__global__ void k_gather(const float* __restrict__ ops, const float* __restrict__ ea,
                         const int2* __restrict__ meta, const int* __restrict__ offs,
                         const float* __restrict__ v, const float* __restrict__ tcross,
                         float* __restrict__ X, float* __restrict__ psum) {
    int r = blockIdx.x;
    int t = threadIdx.x;
    int w = t >> 6, l = t & 63;
    int beg = offs[r], end = offs[r + 1], cnt = end - beg;
    float4 vv = *(const float4*)(v + l * 4);
    float tc = tcross[r];
    __shared__ int2 smeta[256];
    __shared__ float4 lred[4][64];
    __shared__ float lps[4];
    float4 acc = {0.f, 0.f, 0.f, 0.f};
    float ps = 0.f;
    const float* basep = (l < 48) ? ops : ea;
    const int stride = (l < 48) ? DO : DE;
    const int coff = (l < 48) ? l * 4 : (l - 48) * 4;
    for (int base = 0; base < cnt; base += 256) {
        int n = min(256, cnt - base);
        if (t < n) smeta[t] = meta[beg + base + t];
        __syncthreads();
#pragma unroll 4
        for (int j = w; j < n; j += 4) {
            int2 m = smeta[j];
            int row = (l < 48) ? m.x : m.y;
            float4 rv = *(const float4*)(basep + (size_t)row * stride + coff);
            float d = rv.x * vv.x + rv.y * vv.y + rv.z * vv.z + rv.w * vv.w;
            d += __shfl_xor(d, 1, 64);
            d += __shfl_xor(d, 2, 64);
            d += __shfl_xor(d, 4, 64);
            d += __shfl_xor(d, 8, 64);
            d += __shfl_xor(d, 16, 64);
            d += __shfl_xor(d, 32, 64);
            float sc = tc + d;
            float p = expf(sc >= 0.f ? sc : 0.2f * sc);
            ps += p;
            acc.x += p * rv.x; acc.y += p * rv.y;
            acc.z += p * rv.z; acc.w += p * rv.w;
        }
        __syncthreads();
    }
    lred[w][l] = acc;
    if (l == 0) lps[w] = ps;
    __syncthreads();
    if (t < 64) {
        float4 a0 = lred[0][t], a1 = lred[1][t], a2 = lred[2][t], a3 = lred[3][t];
        float4 sum;
        sum.x = (a0.x + a1.x) + (a2.x + a3.x);
        sum.y = (a0.y + a1.y) + (a2.y + a3.y);
        sum.z = (a0.z + a1.z) + (a2.z + a3.z);
        sum.w = (a0.w + a1.w) + (a2.w + a3.w);
        ((float4*)(X + (size_t)r * EMB))[t] = sum;
        if (t == 0) psum[r] = (lps[0] + lps[1]) + (lps[2] + lps[3]);
    }
}

// S = sum(p_self) + sum(psum)
__global__ void k_sum(const float* __restrict__ p_self, const float* __restrict__ psum,
                      int R, float* __restrict__ S) {
    __shared__ float fs[1024];
    int t = threadIdx.x;
    float fv = 0.f;
    for (int i = t; i < R; i += 1024) fv += p_self[i] + psum[i];
    fs[t] = fv;
    __syncthreads();
    for (int off = 512; off > 0; off >>= 1) {
        if (t < off) fs[t] += fs[t + off];
        __syncthreads();
    }
    if (t == 0) *S = fs[0];
}

// out[r][c] = elu( (p_self[r]*h[r][c] + sum_j wT[j][c]*X[r][j]) / S )
__global__ void k_final(const float* __restrict__ X, const float* __restrict__ wT,
                        const float* __restrict__ h, const float* __restrict__ p_self,
                        const float* __restrict__ Sp, float* __restrict__ out, int R) {
    __shared__ float xl[FRPB][EMB];
    __shared__ float ps[FRPB];
    int r0 = blockIdx.x * FRPB;
    int t = threadIdx.x;
    for (int i = t; i < FRPB * EMB; i += 256) {
        int rr = i >> 8, j = i & 255;
        xl[rr][j] = (r0 + rr < R) ? X[(size_t)(r0 + rr) * EMB + j] : 0.f;
    }
    if (t < FRPB) ps[t] = (r0 + t < R) ? p_self[r0 + t] : 0.f;
    __syncthreads();
    float acc[FRPB];
#pragma unroll
    for (int rr = 0; rr < FRPB; rr++) acc[rr] = 0.f;
    int c = t;
    for (int j = 0; j < EMB; j += 4) {
        float w0 = wT[(j + 0) * EMB + c];
        float w1 = wT[(j + 1) * EMB + c];
        float w2 = wT[(j + 2) * EMB + c];
        float w3 = wT[(j + 3) * EMB + c];
#pragma unroll
        for (int rr = 0; rr < FRPB; rr++) {
            float4 xv = *(const float4*)&xl[rr][j];
            acc[rr] += xv.x * w0 + xv.y * w1 + xv.z * w2 + xv.w * w3;
        }
    }
    float inv = 1.f / (*Sp);
#pragma unroll
    for (int rr = 0; rr < FRPB; rr++) {
        int r = r0 + rr;
        if (r < R) {
            float val = (ps[rr] * h[(size_t)r * EMB + c] + acc[rr]) * inv;
            out[(size_t)r * EMB + c] = val > 0.f ? val : expm1f(val);
        }
    }
}

extern "C" void kernel_launch(void* const* d_in, const int* in_sizes, int n_in,
                              void* d_out, int out_size, void* d_ws, size_t ws_size,
                              hipStream_t stream) {
    const float* resources = (const float*)d_in[0];
    const float* operations = (const float*)d_in[1];
    const float* edge_attr = (const float*)d_in[2];
    const float* W_self = (const float*)d_in[3];
    const float* W_op = (const float*)d_in[4];
    const float* a_self = (const float*)d_in[5];
    const float* a_op = (const float*)d_in[6];
    const int* edge_src = (const int*)d_in[7];
    const int* edge_dst = (const int*)d_in[8];
    float* out = (float*)d_out;

    const int R = in_sizes[0] / DR;
    const int O = in_sizes[1] / DO;  (void)O;
    const int E = in_sizes[2] / DE;

    // workspace carve — counts and v first so one memset zeroes both
    int* counts = (int*)d_ws;                 // R
    float* v = (float*)(counts + R);          // 256
    float* wsT = v + EMB;                     // 128*256
    float* wT = wsT + DR * EMB;               // 256*256
    float* h = wT + EMB * EMB;                // R*256
    float* X = h + (size_t)R * EMB;           // R*256
    float* tcross = X + (size_t)R * EMB;      // R
    float* p_self = tcross + R;               // R
    float* psum = p_self + R;                 // R
    float* S = psum + R;                      // 1
    int* offs = (int*)(S + 1);                // R+1
    int* cursor = offs + R + 1;               // R
    int2* meta = (int2*)(cursor + R);         // E (8B each)

    hipMemsetAsync(d_ws, 0, (size_t)(R + EMB) * sizeof(float), stream);

    k_prep<<<416 + HB, 256, 0, stream>>>(wsT, wT, v, W_self, W_op, a_op, edge_dst,
                                         counts, E);
    k_h<<<(R + RPB - 1) / RPB, EMB, 0, stream>>>(resources, wsT, a_self, a_op, h,
                                                 tcross, p_self, R);
    k_scan<<<1, 1024, 0, stream>>>(counts, offs, cursor, R);
    k_scatter<<<1024, 256, 0, stream>>>(edge_dst, edge_src, cursor, meta, E);
    k_gather<<<R, 256, 0, stream>>>(operations, edge_attr, meta, offs, v, tcross, X, psum);
    k_sum<<<1, 1024, 0, stream>>>(p_self, psum, R, S);
    k_final<<<(R + FRPB - 1) / FRPB, 256, 0, stream>>>(X, wT, h, p_self, S, out, R);
}